// Round 1
// baseline (343.301 us; speedup 1.0000x reference)
//
#include <hip/hip_runtime.h>
#include <math.h>

#define BB 128
#define PP 8732
#define CC 21
#define NNO 16
#define THRESH 0.5f

__device__ __forceinline__ float sl1(float d) {
    float a = fabsf(d);
    return (a < 1.0f) ? 0.5f * a * a : a - 0.5f;
}

// ---------------- Kernel A: matching + loc loss ----------------
__global__ __launch_bounds__(256) void k_match(
    const float4* __restrict__ loc_data,   // [B*P]
    const float4* __restrict__ priors,     // [P]
    const float4* __restrict__ truths,     // [B*NO]
    const int*    __restrict__ labels,     // [B*NO]
    unsigned char* __restrict__ conf_t,    // [B*P]
    int*   __restrict__ num_pos,           // [B]
    float* __restrict__ loss_l_acc,
    int*   __restrict__ total_pos)
{
    __shared__ float          s_bov[PP];
    __shared__ unsigned char  s_bidx[PP];
    __shared__ float4         s_t[NNO];
    __shared__ float          s_at[NNO];
    __shared__ int            s_lab[NNO];
    __shared__ float          s_rv[4][NNO];
    __shared__ int            s_ri[4][NNO];
    __shared__ int            s_bpi[NNO];
    __shared__ float          s_red[4];
    __shared__ int            s_redi[4];

    const int b   = blockIdx.x;
    const int tid = threadIdx.x;

    if (tid < NNO) {
        float4 t = truths[b * NNO + tid];
        s_t[tid]   = t;
        s_at[tid]  = (t.z - t.x) * (t.w - t.y);
        s_lab[tid] = labels[b * NNO + tid];
    }
    __syncthreads();

    float bpV[NNO];
    int   bpI[NNO];
#pragma unroll
    for (int j = 0; j < NNO; j++) { bpV[j] = -1.0f; bpI[j] = 0; }

    for (int p = tid; p < PP; p += 256) {
        float4 pr = priors[p];
        float px0 = pr.x - pr.z * 0.5f;
        float py0 = pr.y - pr.w * 0.5f;
        float px1 = pr.x + pr.z * 0.5f;
        float py1 = pr.y + pr.w * 0.5f;
        float ap  = (px1 - px0) * (py1 - py0);
        float bov = -1.0f; int bidx = 0;
#pragma unroll
        for (int j = 0; j < NNO; j++) {
            float4 t = s_t[j];
            float ix0 = fmaxf(t.x, px0);
            float iy0 = fmaxf(t.y, py0);
            float ix1 = fminf(t.z, px1);
            float iy1 = fminf(t.w, py1);
            float iw = fmaxf(ix1 - ix0, 0.0f);
            float ih = fmaxf(iy1 - iy0, 0.0f);
            float inter = iw * ih;
            float ov = inter / (s_at[j] + ap - inter);
            if (ov > bov) { bov = ov; bidx = j; }              // argmax over truths, first-index
            if (ov > bpV[j]) { bpV[j] = ov; bpI[j] = p; }      // per-truth best prior (p ascending)
        }
        s_bov[p]  = bov;
        s_bidx[p] = (unsigned char)bidx;
    }

    // reduce per-truth best prior across block (tie-break: smaller prior index)
    const int lane = tid & 63;
    const int wv   = tid >> 6;
#pragma unroll
    for (int j = 0; j < NNO; j++) {
        float v = bpV[j]; int idx = bpI[j];
#pragma unroll
        for (int off = 32; off >= 1; off >>= 1) {
            float ov = __shfl_down(v, off);
            int   oi = __shfl_down(idx, off);
            if (ov > v || (ov == v && oi < idx)) { v = ov; idx = oi; }
        }
        if (lane == 0) { s_rv[wv][j] = v; s_ri[wv][j] = idx; }
    }
    __syncthreads();
    if (tid < NNO) {
        float v = s_rv[0][tid]; int idx = s_ri[0][tid];
        for (int w = 1; w < 4; w++) {
            float ov = s_rv[w][tid]; int oi = s_ri[w][tid];
            if (ov > v || (ov == v && oi < idx)) { v = ov; idx = oi; }
        }
        s_bpi[tid] = idx;
    }
    __syncthreads();

    // phase 3: forced override, conf targets, loc loss over positives
    float lsum = 0.0f;
    int   np   = 0;
    for (int p = tid; p < PP; p += 256) {
        float ov = s_bov[p];
        int   idx = s_bidx[p];
        int forced = -1;
#pragma unroll
        for (int j = 0; j < NNO; j++) if (s_bpi[j] == p) forced = j;  // scatter-max of j
        if (forced >= 0) { idx = forced; ov = 2.0f; }
        int lab = (ov < THRESH) ? 0 : s_lab[idx];
        conf_t[(size_t)b * PP + p] = (unsigned char)lab;
        if (lab > 0) {
            np++;
            float4 t  = s_t[idx];
            float4 pr = priors[p];
            float g0 = ((t.x + t.z) * 0.5f - pr.x) / (0.1f * pr.z);
            float g1 = ((t.y + t.w) * 0.5f - pr.y) / (0.1f * pr.w);
            float g2 = logf((t.z - t.x) / pr.z) / 0.2f;
            float g3 = logf((t.w - t.y) / pr.w) / 0.2f;
            float4 ld = loc_data[(size_t)b * PP + p];
            lsum += sl1(ld.x - g0) + sl1(ld.y - g1) + sl1(ld.z - g2) + sl1(ld.w - g3);
        }
    }
#pragma unroll
    for (int off = 32; off >= 1; off >>= 1) {
        lsum += __shfl_down(lsum, off);
        np   += __shfl_down(np, off);
    }
    if (lane == 0) { s_red[wv] = lsum; s_redi[wv] = np; }
    __syncthreads();
    if (tid == 0) {
        float L = s_red[0] + s_red[1] + s_red[2] + s_red[3];
        int   N = s_redi[0] + s_redi[1] + s_redi[2] + s_redi[3];
        num_pos[b] = N;
        atomicAdd(total_pos, N);
        atomicAdd(loss_l_acc, L);
    }
}

// ---------------- Kernel B: per-row LSE, mining scores, positive CE ----------------
__global__ __launch_bounds__(256) void k_conf(
    const float* __restrict__ conf_data,   // [B*P*C]
    const unsigned char* __restrict__ conf_t,
    float* __restrict__ loss_c,            // [B*P]
    float* __restrict__ loss_c_acc)
{
    __shared__ float s_x[256 * CC];
    __shared__ float s_red[4];
    const int r0  = blockIdx.x * 256;
    const int tid = threadIdx.x;

    const float* src = conf_data + (size_t)r0 * CC;
    for (int i = tid; i < 256 * CC; i += 256) s_x[i] = src[i];
    __syncthreads();

    const float* x = s_x + tid * CC;
    float m = x[0];
#pragma unroll
    for (int c = 1; c < CC; c++) m = fmaxf(m, x[c]);
    float s = 0.0f;
#pragma unroll
    for (int c = 0; c < CC; c++) s += expf(x[c] - m);
    float lse = logf(s) + m;

    int ct = (int)conf_t[r0 + tid];
    float lc    = (ct > 0) ? 0.0f : (lse - x[0]);
    float posce = (ct > 0) ? (lse - x[ct]) : 0.0f;
    loss_c[r0 + tid] = lc;

#pragma unroll
    for (int off = 32; off >= 1; off >>= 1) posce += __shfl_down(posce, off);
    const int lane = tid & 63, wv = tid >> 6;
    if (lane == 0) s_red[wv] = posce;
    __syncthreads();
    if (tid == 0) atomicAdd(loss_c_acc, s_red[0] + s_red[1] + s_red[2] + s_red[3]);
}

// ---------------- Kernel C: hard-negative mining (top-k sum via radix select) ----------------
__global__ __launch_bounds__(256) void k_mine(
    const float* __restrict__ loss_c,
    const int*   __restrict__ num_pos,
    float* __restrict__ loss_c_acc)
{
    __shared__ float    s_v[PP];
    __shared__ int      s_hist[256];
    __shared__ unsigned s_pref;
    __shared__ int      s_kp;
    __shared__ float    s_red[4];
    __shared__ int      s_redi[4];

    const int b   = blockIdx.x;
    const int tid = threadIdx.x;

    const float* src = loss_c + (size_t)b * PP;
    for (int i = tid; i < PP; i += 256) s_v[i] = src[i];
    int k = num_pos[b] * 3;
    if (k > PP - 1) k = PP - 1;
    __syncthreads();
    if (k <= 0) return;   // uniform across block

    unsigned prefix = 0, mask = 0;
    int kp = k;
    for (int shift = 24; shift >= 0; shift -= 8) {
        s_hist[tid & 255] = 0;
        __syncthreads();
        for (int i = tid; i < PP; i += 256) {
            unsigned u = __float_as_uint(s_v[i]);   // all values >= 0 -> integer order == float order
            if ((u & mask) == prefix) atomicAdd(&s_hist[(u >> shift) & 255], 1);
        }
        __syncthreads();
        if (tid == 0) {
            int cum = 0;
            for (int bin = 255; bin >= 0; bin--) {
                int h = s_hist[bin];
                if (cum + h >= kp) {
                    s_pref = prefix | ((unsigned)bin << shift);
                    s_kp   = kp - cum;
                    break;
                }
                cum += h;
            }
        }
        __syncthreads();
        prefix = s_pref;
        kp     = s_kp;
        mask  |= (0xFFu << shift);
        __syncthreads();
    }

    const float T = __uint_as_float(prefix);   // k-th largest value
    float sum = 0.0f; int cnt = 0;
    for (int i = tid; i < PP; i += 256) {
        float v = s_v[i];
        if (v > T) { sum += v; cnt++; }
    }
#pragma unroll
    for (int off = 32; off >= 1; off >>= 1) {
        sum += __shfl_down(sum, off);
        cnt += __shfl_down(cnt, off);
    }
    const int lane = tid & 63, wv = tid >> 6;
    if (lane == 0) { s_red[wv] = sum; s_redi[wv] = cnt; }
    __syncthreads();
    if (tid == 0) {
        float S = s_red[0] + s_red[1] + s_red[2] + s_red[3];
        int   G = s_redi[0] + s_redi[1] + s_redi[2] + s_redi[3];
        atomicAdd(loss_c_acc, S + (float)(k - G) * T);   // exact tie handling at the cutoff
    }
}

// ---------------- Kernel D: finalize ----------------
__global__ void k_final(const float* __restrict__ acc, const int* __restrict__ total_pos,
                        float* __restrict__ out)
{
    float N = (float)total_pos[0];
    if (N < 1.0f) N = 1.0f;
    out[0] = acc[0] / N;
    out[1] = acc[1] / N;
}

extern "C" void kernel_launch(void* const* d_in, const int* in_sizes, int n_in,
                              void* d_out, int out_size, void* d_ws, size_t ws_size,
                              hipStream_t stream)
{
    const float4* loc    = (const float4*)d_in[0];
    const float*  conf   = (const float*)d_in[1];
    const float4* priors = (const float4*)d_in[2];
    const float4* truths = (const float4*)d_in[3];
    const int*    labels = (const int*)d_in[4];
    float* out = (float*)d_out;

    char* ws = (char*)d_ws;
    // layout: [0..7] float acc{loss_l, loss_c}; [8..11] int total_pos;
    //         [64..] int num_pos[B]; [1024..] u8 conf_t[B*P]; then float loss_c[B*P]
    float*         acc       = (float*)ws;
    int*           total_pos = (int*)(ws + 8);
    int*           num_pos   = (int*)(ws + 64);
    unsigned char* conf_t    = (unsigned char*)(ws + 1024);
    size_t ct_bytes = ((size_t)BB * PP + 255) & ~(size_t)255;
    float*         loss_c    = (float*)(ws + 1024 + ct_bytes);

    hipMemsetAsync(d_ws, 0, 1024, stream);
    k_match<<<BB, 256, 0, stream>>>(loc, priors, truths, labels, conf_t, num_pos, acc, total_pos);
    k_conf<<<(BB * PP) / 256, 256, 0, stream>>>(conf, conf_t, loss_c, acc + 1);
    k_mine<<<BB, 256, 0, stream>>>(loss_c, num_pos, acc + 1);
    k_final<<<1, 1, 0, stream>>>(acc, total_pos, out);
}